// Round 13
// baseline (527.040 us; speedup 1.0000x reference)
//
#include <hip/hip_runtime.h>

// Established: all float inputs fp32, output fp32, mask int32. ws >= 256MB.
#define B_   4
#define S_   1024
#define D_   512
#define H_   8
#define DH_  64
#define L_   4
#define NTOK (B_ * S_)            // 4096 tokens
#define NT   (NTOK * D_)          // 2097152 elems per activation
#define DD   (D_ * D_)            // 262144 elems per weight matrix

typedef __attribute__((ext_vector_type(8))) short bf16x8;
typedef __attribute__((ext_vector_type(4))) float f32x4;

// async global->LDS, 16B per lane; LDS dest = wave-uniform base + lane*16
#define GLL(gp, lp)                                                            \
    __builtin_amdgcn_global_load_lds(                                          \
        (const __attribute__((address_space(1))) unsigned int*)(gp),           \
        (__attribute__((address_space(3))) unsigned int*)(lp), 16, 0, 0)

// ---------- bf16 helpers ----------
__device__ __forceinline__ float us2f(unsigned short u) {
    unsigned int v = ((unsigned int)u) << 16;
    return __uint_as_float(v);
}
__device__ __forceinline__ unsigned short f2us(float f) {
    unsigned int u = __float_as_uint(f);
    unsigned int r = (u + 0x7fffu + ((u >> 16) & 1u)) >> 16;
    return (unsigned short)r;
}
__device__ __forceinline__ void stv(float* p, float v) { *p = v; }
__device__ __forceinline__ void stv(unsigned short* p, float v) { *p = f2us(v); }

// ---------- upfront: convert all 24 weight matrices fp32 -> bf16 ----------
struct WConvArgs { const float* in[6]; };
__global__ __launch_bounds__(256) void wconv24_k(WConvArgs a, unsigned short* __restrict__ out) {
    int y = blockIdx.y;                      // y = l*6 + t
    int l = y / 6, tp = y - l * 6;
    int i = (blockIdx.x * 256 + threadIdx.x) * 4;
    float4 v = *(const float4*)(a.in[tp] + (size_t)l * DD + i);
    ushort4 o;
    o.x = f2us(v.x); o.y = f2us(v.y); o.z = f2us(v.z); o.w = f2us(v.w);
    *(ushort4*)(out + (size_t)y * DD + i) = o;
}

// ---------- first layer: copy src -> srcf AND LN1 -> zb in one pass ----------
__global__ __launch_bounds__(256) void lncpy_k(const float* __restrict__ x,
                                               const float* __restrict__ w,
                                               const float* __restrict__ b,
                                               float* __restrict__ xc,
                                               unsigned short* __restrict__ z) {
    int wv = threadIdx.x >> 6, lane = threadIdx.x & 63;
    int tok = blockIdx.x * 4 + wv;
    const float* xr = x + (size_t)tok * D_;
    float v[8];
    float s = 0.f, s2 = 0.f;
#pragma unroll
    for (int i = 0; i < 8; ++i) {
        float t = xr[lane + 64 * i];
        v[i] = t; s += t; s2 += t * t;
    }
#pragma unroll
    for (int o = 1; o < 64; o <<= 1) { s += __shfl_xor(s, o); s2 += __shfl_xor(s2, o); }
    float mu = s * (1.f / D_);
    float var = s2 * (1.f / D_) - mu * mu;
    float rs = rsqrtf(var + 1e-5f);
#pragma unroll
    for (int i = 0; i < 8; ++i) {
        int d = lane + 64 * i;
        xc[(size_t)tok * D_ + d] = v[i];
        z[(size_t)tok * D_ + d] = f2us((v[i] - mu) * rs * w[d] + b[d]);
    }
}

// ---------- LayerNorm: one wave per token ----------
template <typename OutT>
__global__ __launch_bounds__(256) void ln_k(const float* __restrict__ x,
                                            const float* __restrict__ w,
                                            const float* __restrict__ b,
                                            OutT* __restrict__ y) {
    int wv = threadIdx.x >> 6, lane = threadIdx.x & 63;
    int tok = blockIdx.x * 4 + wv;
    const float* xr = x + (size_t)tok * D_;
    float v[8];
    float s = 0.f, s2 = 0.f;
#pragma unroll
    for (int i = 0; i < 8; ++i) {
        float t = xr[lane + 64 * i];
        v[i] = t; s += t; s2 += t * t;
    }
#pragma unroll
    for (int o = 1; o < 64; o <<= 1) { s += __shfl_xor(s, o); s2 += __shfl_xor(s2, o); }
    float mu = s * (1.f / D_);
    float var = s2 * (1.f / D_) - mu * mu;
    float rs = rsqrtf(var + 1e-5f);
#pragma unroll
    for (int i = 0; i < 8; ++i) {
        int d = lane + 64 * i;
        stv(y + (size_t)tok * D_ + d, (v[i] - mu) * rs * w[d] + b[d]);
    }
}

// ---------- fused LN3 (layer l) + LN1 (layer l+1): srcf -> srcf & zb ----------
__global__ __launch_bounds__(256) void ln31_k(const float* __restrict__ x,
                                              const float* __restrict__ w3,
                                              const float* __restrict__ b3,
                                              const float* __restrict__ w1,
                                              const float* __restrict__ b1,
                                              float* __restrict__ y,
                                              unsigned short* __restrict__ z) {
    int wv = threadIdx.x >> 6, lane = threadIdx.x & 63;
    int tok = blockIdx.x * 4 + wv;
    const float* xr = x + (size_t)tok * D_;
    float v[8];
    float s = 0.f, s2 = 0.f;
#pragma unroll
    for (int i = 0; i < 8; ++i) {
        float t = xr[lane + 64 * i];
        v[i] = t; s += t; s2 += t * t;
    }
#pragma unroll
    for (int o = 1; o < 64; o <<= 1) { s += __shfl_xor(s, o); s2 += __shfl_xor(s2, o); }
    float mu = s * (1.f / D_);
    float var = s2 * (1.f / D_) - mu * mu;
    float rs = rsqrtf(var + 1e-5f);
    float yv[8];
    s = 0.f; s2 = 0.f;
#pragma unroll
    for (int i = 0; i < 8; ++i) {
        int d = lane + 64 * i;
        float t = (v[i] - mu) * rs * w3[d] + b3[d];
        yv[i] = t; s += t; s2 += t * t;
    }
#pragma unroll
    for (int o = 1; o < 64; o <<= 1) { s += __shfl_xor(s, o); s2 += __shfl_xor(s2, o); }
    float mu1 = s * (1.f / D_);
    float var1 = s2 * (1.f / D_) - mu1 * mu1;
    float rs1 = rsqrtf(var1 + 1e-5f);
#pragma unroll
    for (int i = 0; i < 8; ++i) {
        int d = lane + 64 * i;
        y[(size_t)tok * D_ + d] = yv[i];
        z[(size_t)tok * D_ + d] = f2us((yv[i] - mu1) * rs1 * w1[d] + b1[d]);
    }
}

// ---------- fused LN2 + tanh + cubic B-spline -> bf16 inner ----------
__global__ __launch_bounds__(256) void kan_k(const float* __restrict__ x,
                                             const float* __restrict__ w,
                                             const float* __restrict__ b,
                                             const float* __restrict__ ic,
                                             unsigned short* __restrict__ inner) {
    int wv = threadIdx.x >> 6, lane = threadIdx.x & 63;
    int tok = blockIdx.x * 4 + wv;
    const float* xr = x + (size_t)tok * D_;
    float v[8];
    float s = 0.f, s2 = 0.f;
#pragma unroll
    for (int i = 0; i < 8; ++i) {
        float t = xr[lane + 64 * i];
        v[i] = t; s += t; s2 += t * t;
    }
#pragma unroll
    for (int o = 1; o < 64; o <<= 1) { s += __shfl_xor(s, o); s2 += __shfl_xor(s2, o); }
    float mu = s * (1.f / D_);
    float var = s2 * (1.f / D_) - mu * mu;
    float rs = rsqrtf(var + 1e-5f);

    const float kn[8] = {-1.f,
                         -0.71428571428571430f, -0.42857142857142855f, -0.14285714285714285f,
                          0.14285714285714285f,  0.42857142857142855f,  0.71428571428571430f,
                          1.f};
#pragma unroll
    for (int i = 0; i < 8; ++i) {
        int d = lane + 64 * i;
        float zv = (v[i] - mu) * rs * w[d] + b[d];
        float xt = tanhf(zv);
        float B0[5];
#pragma unroll
        for (int k = 0; k < 5; ++k) B0[k] = (kn[k] <= xt && xt < kn[k + 1]) ? 1.f : 0.f;
        float B1[4];
#pragma unroll
        for (int k = 0; k < 4; ++k)
            B1[k] = (xt - kn[k]) / (kn[k + 1] - kn[k]) * B0[k] +
                    (kn[k + 2] - xt) / (kn[k + 2] - kn[k + 1]) * B0[k + 1];
        float B2[3];
#pragma unroll
        for (int k = 0; k < 3; ++k)
            B2[k] = (xt - kn[k]) / (kn[k + 2] - kn[k]) * B1[k] +
                    (kn[k + 3] - xt) / (kn[k + 3] - kn[k + 1]) * B1[k + 1];
        float B3[2];
#pragma unroll
        for (int k = 0; k < 2; ++k)
            B3[k] = (xt - kn[k]) / (kn[k + 3] - kn[k]) * B2[k] +
                    (kn[k + 4] - xt) / (kn[k + 4] - kn[k + 1]) * B2[k + 1];
        inner[(size_t)tok * D_ + d] = f2us(B3[0] * ic[d * 5 + 0] + B3[1] * ic[d * 5 + 1]);
    }
}

// ---------- MFMA GEMM A: 128x128 tile, BK=32, double-buffered GLL (QKVR) ----------
struct MGemm128Args {
    const unsigned short* A;
    const unsigned short* W[4];
    const float* bias[4];
    unsigned short* C[4];
    int tflag[4];
};

__global__ __launch_bounds__(256) void mgemm128_k(MGemm128Args g) {
    __shared__ unsigned short As[2][128 * 32];
    __shared__ unsigned short Bs[2][128 * 32];
    int z = blockIdx.z;
    const unsigned short* W = g.W[z];
    const float* bias = g.bias[z];
    unsigned short* C = g.C[z];
    int m0 = blockIdx.y * 128, n0 = blockIdx.x * 128;
    int t = threadIdx.x;
    int wave = t >> 6, lane = t & 63;
    int wm = (wave >> 1) * 64, wn = (wave & 1) * 64;
    int l15 = lane & 15, quad = lane >> 4;
    int lrow = lane >> 2, lk = (lane & 3) * 8;

    f32x4 acc[4][4];
#pragma unroll
    for (int i = 0; i < 4; ++i)
#pragma unroll
        for (int j = 0; j < 4; ++j)
#pragma unroll
            for (int r = 0; r < 4; ++r) acc[i][j][r] = 0.f;

    int rb = wave * 32;
    const unsigned short* Ag1 = g.A + (size_t)(m0 + rb + lrow) * D_ + lk;
    const unsigned short* Ag2 = g.A + (size_t)(m0 + rb + 16 + lrow) * D_ + lk;
    const unsigned short* Wg1 = W + (size_t)(n0 + rb + lrow) * D_ + lk;
    const unsigned short* Wg2 = W + (size_t)(n0 + rb + 16 + lrow) * D_ + lk;

    // prologue: stage k0=0 into buffer 0
    GLL(Ag1, &As[0][rb * 32]);
    GLL(Ag2, &As[0][(rb + 16) * 32]);
    GLL(Wg1, &Bs[0][rb * 32]);
    GLL(Wg2, &Bs[0][(rb + 16) * 32]);

    for (int it = 0; it < 16; ++it) {
        int cur = it & 1;
        __syncthreads();   // drains buf[cur] staging (issued one compute-phase ago)
        if (it < 15) {
            int kn = (it + 1) * 32;
            int nb = 1 - cur;
            GLL(Ag1 + kn, &As[nb][rb * 32]);
            GLL(Ag2 + kn, &As[nb][(rb + 16) * 32]);
            GLL(Wg1 + kn, &Bs[nb][rb * 32]);
            GLL(Wg2 + kn, &Bs[nb][(rb + 16) * 32]);
        }
        bf16x8 af[4], bfr[4];
#pragma unroll
        for (int mt = 0; mt < 4; ++mt)
            af[mt] = *(const bf16x8*)&As[cur][(wm + mt * 16 + l15) * 32 + quad * 8];
#pragma unroll
        for (int nt = 0; nt < 4; ++nt)
            bfr[nt] = *(const bf16x8*)&Bs[cur][(wn + nt * 16 + l15) * 32 + quad * 8];
#pragma unroll
        for (int mt = 0; mt < 4; ++mt)
#pragma unroll
            for (int nt = 0; nt < 4; ++nt)
                acc[mt][nt] = __builtin_amdgcn_mfma_f32_16x16x32_bf16(
                    af[mt], bfr[nt], acc[mt][nt], 0, 0, 0);
    }

    if (g.tflag[z]) {
#pragma unroll
        for (int mt = 0; mt < 4; ++mt)
#pragma unroll
            for (int nt = 0; nt < 4; ++nt) {
                int n = n0 + wn + nt * 16 + l15;
                float bv = bias[n];
                int m = m0 + wm + mt * 16 + quad * 4;
                ushort4 pk;
                pk.x = f2us(acc[mt][nt][0] + bv);
                pk.y = f2us(acc[mt][nt][1] + bv);
                pk.z = f2us(acc[mt][nt][2] + bv);
                pk.w = f2us(acc[mt][nt][3] + bv);
                *(ushort4*)(C + ((size_t)(m >> 10) * 512 + n) * 1024 + (m & 1023)) = pk;
            }
    } else {
#pragma unroll
        for (int mt = 0; mt < 4; ++mt)
#pragma unroll
            for (int nt = 0; nt < 4; ++nt) {
                int n = n0 + wn + nt * 16 + l15;
                float bv = bias[n];
#pragma unroll
                for (int r = 0; r < 4; ++r) {
                    int m = m0 + wm + mt * 16 + quad * 4 + r;
                    C[(size_t)m * D_ + n] = f2us(acc[mt][nt][r] + bv);
                }
            }
    }
}

// ---------- MFMA GEMM B: 64x64 tile, double-buffered GLL (wo/oc; 512 blocks) ----------
struct MGemm64Args {
    const unsigned short* A;
    const unsigned short* W;
    const float* bias;
    const float* res;
    float* C;
};

__global__ __launch_bounds__(256) void mgemm64_k(MGemm64Args g) {
    __shared__ unsigned short As[2][64 * 32];
    __shared__ unsigned short Bs[2][64 * 32];
    int m0 = blockIdx.y * 64, n0 = blockIdx.x * 64;
    int t = threadIdx.x;
    int wave = t >> 6, lane = t & 63;
    int wm = (wave >> 1) * 32, wn = (wave & 1) * 32;
    int fm = lane & 15, fq = (lane >> 4) * 8;
    // staging: wave stages rows wave*16..+15; lane>>2 row off, (lane&3)*8 chunk
    int srow = wave * 16 + (lane >> 2);
    int sk = (lane & 3) * 8;
    int sbase = (wave * 16) * 32;
    const unsigned short* Ag = g.A + (size_t)(m0 + srow) * D_ + sk;
    const unsigned short* Wg = g.W + (size_t)(n0 + srow) * D_ + sk;

    f32x4 acc[2][2];
#pragma unroll
    for (int i = 0; i < 2; ++i)
#pragma unroll
        for (int j = 0; j < 2; ++j)
#pragma unroll
            for (int r = 0; r < 4; ++r) acc[i][j][r] = 0.f;

    GLL(Ag, &As[0][sbase]);
    GLL(Wg, &Bs[0][sbase]);

    for (int it = 0; it < 16; ++it) {
        int cur = it & 1;
        __syncthreads();
        if (it < 15) {
            int kn = (it + 1) * 32;
            GLL(Ag + kn, &As[1 - cur][sbase]);
            GLL(Wg + kn, &Bs[1 - cur][sbase]);
        }
        bf16x8 a0 = *(const bf16x8*)&As[cur][(wm + fm) * 32 + fq];
        bf16x8 a1 = *(const bf16x8*)&As[cur][(wm + 16 + fm) * 32 + fq];
        bf16x8 b0 = *(const bf16x8*)&Bs[cur][(wn + fm) * 32 + fq];
        bf16x8 b1 = *(const bf16x8*)&Bs[cur][(wn + 16 + fm) * 32 + fq];
        acc[0][0] = __builtin_amdgcn_mfma_f32_16x16x32_bf16(a0, b0, acc[0][0], 0, 0, 0);
        acc[0][1] = __builtin_amdgcn_mfma_f32_16x16x32_bf16(a0, b1, acc[0][1], 0, 0, 0);
        acc[1][0] = __builtin_amdgcn_mfma_f32_16x16x32_bf16(a1, b0, acc[1][0], 0, 0, 0);
        acc[1][1] = __builtin_amdgcn_mfma_f32_16x16x32_bf16(a1, b1, acc[1][1], 0, 0, 0);
    }

    int col = lane & 15, rbase = (lane >> 4) * 4;
#pragma unroll
    for (int i = 0; i < 2; ++i)
#pragma unroll
        for (int j = 0; j < 2; ++j) {
            int n = n0 + wn + j * 16 + col;
            float bv = g.bias ? g.bias[n] : 0.f;
#pragma unroll
            for (int r = 0; r < 4; ++r) {
                int m = m0 + wm + i * 16 + rbase + r;
                g.C[(size_t)m * D_ + n] = acc[i][j][r] + bv + g.res[(size_t)m * D_ + n];
            }
        }
}

// ---------- MFMA flash attention, softmax-lite, double-buffered GLL K/V ----------
// XOR swizzle on GLOBAL source chunk (LDS chunk j of row r holds global chunk
// j ^ (r&7)); frag reads use chunk ((kc*4+quad) ^ (l15&7)). Mask staged once.
// vt layout: vt[(b*512 + h*64 + d)*1024 + s]
__global__ __launch_bounds__(256) void attn_k(const unsigned short* __restrict__ Q,
                                              const unsigned short* __restrict__ K,
                                              const unsigned short* __restrict__ vt,
                                              const unsigned short* __restrict__ R,
                                              const int* __restrict__ mask,
                                              unsigned short* __restrict__ O) {
    __shared__ unsigned short Ks[2][64 * 64];
    __shared__ unsigned short Vts[2][64 * 64];
    __shared__ unsigned short Ps[4][16][72];
    __shared__ float Ms[1024];   // whole mask row for this b

    int bh = blockIdx.x;
    int b = bh >> 3, h = bh & 7;
    int qt0 = blockIdx.y * 64;
    int t = threadIdx.x, wave = t >> 6, lane = t & 63;
    int l15 = lane & 15, quad = lane >> 4;
    int qw0 = qt0 + wave * 16;

    const unsigned short* Qrow = Q + ((size_t)(b * S_ + qw0 + l15) * H_ + h) * DH_;
    bf16x8 qf[2];
    qf[0] = *(const bf16x8*)(Qrow + quad * 8);
    qf[1] = *(const bf16x8*)(Qrow + 32 + quad * 8);

    // stage all 1024 mask adds once
#pragma unroll
    for (int u = 0; u < 4; ++u)
        Ms[u * 256 + t] = mask[b * S_ + u * 256 + t] ? 0.f : -1e10f;

    float lsum[4] = {0.f, 0.f, 0.f, 0.f};
    f32x4 acc_o[4];
#pragma unroll
    for (int dt = 0; dt < 4; ++dt)
#pragma unroll
        for (int r = 0; r < 4; ++r) acc_o[dt][r] = 0.f;

    // GLL staging lane map
    int lro = lane >> 3;
    int cglob = (lane & 7) ^ lro;
    const unsigned short* kgp0 =
        K + ((size_t)(b * S_ + wave * 16 + lro) * H_ + h) * DH_ + cglob * 8;
    const unsigned short* vgp0 =
        vt + (size_t)(b * 512 + h * 64 + wave * 16 + lro) * 1024 + cglob * 8;
    int swz = l15 & 7;

    // prologue: tile 0 -> buffer 0
    GLL(kgp0,                &Ks[0][(wave * 16) * 64]);
    GLL(kgp0 + 8 * 512,      &Ks[0][(wave * 16 + 8) * 64]);
    GLL(vgp0,                &Vts[0][(wave * 16) * 64]);
    GLL(vgp0 + 8 * 1024,     &Vts[0][(wave * 16 + 8) * 64]);

    for (int kt = 0; kt < 16; ++kt) {
        int cur = kt & 1;
        __syncthreads();   // drains tile-kt staging (hidden behind prev compute)
        if (kt < 15) {
            int nb = 1 - cur;
            size_t ko = (size_t)(kt + 1) * 64 * 512;
            GLL(kgp0 + ko,             &Ks[nb][(wave * 16) * 64]);
            GLL(kgp0 + ko + 8 * 512,   &Ks[nb][(wave * 16 + 8) * 64]);
            GLL(vgp0 + (kt + 1) * 64,             &Vts[nb][(wave * 16) * 64]);
            GLL(vgp0 + (kt + 1) * 64 + 8 * 1024,  &Vts[nb][(wave * 16 + 8) * 64]);
        }

        // S = Q @ K^T
        f32x4 accs[4];
#pragma unroll
        for (int jt = 0; jt < 4; ++jt)
#pragma unroll
            for (int r = 0; r < 4; ++r) accs[jt][r] = 0.f;
#pragma unroll
        for (int kc = 0; kc < 2; ++kc) {
            int ch = ((kc * 4 + quad) ^ swz) * 8;
#pragma unroll
            for (int jt = 0; jt < 4; ++jt) {
                bf16x8 kf = *(const bf16x8*)&Ks[cur][(jt * 16 + l15) * 64 + ch];
                accs[jt] = __builtin_amdgcn_mfma_f32_16x16x32_bf16(qf[kc], kf, accs[jt], 0, 0, 0);
            }
        }

        // softmax-lite
#pragma unroll
        for (int jt = 0; jt < 4; ++jt) {
            float madd = Ms[kt * 64 + jt * 16 + l15];
#pragma unroll
            for (int r = 0; r < 4; ++r) {
                float p = __expf(accs[jt][r] * 0.125f + madd);
                lsum[r] += p;
                Ps[wave][quad * 4 + r][jt * 16 + l15] = f2us(p);
            }
        }

        // O += P @ V
#pragma unroll
        for (int kc = 0; kc < 2; ++kc) {
            bf16x8 pf = *(const bf16x8*)&Ps[wave][l15][kc * 32 + quad * 8];
            int ch = ((kc * 4 + quad) ^ swz) * 8;
#pragma unroll
            for (int dt = 0; dt < 4; ++dt) {
                bf16x8 vf = *(const bf16x8*)&Vts[cur][(dt * 16 + l15) * 64 + ch];
                acc_o[dt] = __builtin_amdgcn_mfma_f32_16x16x32_bf16(pf, vf, acc_o[dt], 0, 0, 0);
            }
        }
    }

#pragma unroll
    for (int off = 1; off < 16; off <<= 1)
#pragma unroll
        for (int r = 0; r < 4; ++r) lsum[r] += __shfl_xor(lsum[r], off);

#pragma unroll
    for (int r = 0; r < 4; ++r) {
        int q = qw0 + quad * 4 + r;
        float inv = 1.f / lsum[r];
        const unsigned short* Rr = R + ((size_t)(b * S_ + q) * H_ + h) * DH_;
        unsigned short* Or = O + ((size_t)(b * S_ + q) * H_ + h) * DH_;
#pragma unroll
        for (int dt = 0; dt < 4; ++dt) {
            int d = dt * 16 + l15;
            Or[d] = f2us(acc_o[dt][r] * inv * us2f(Rr[d]));
        }
    }
}

extern "C" void kernel_launch(void* const* d_in, const int* in_sizes, int n_in,
                              void* d_out, int out_size, void* d_ws, size_t ws_size,
                              hipStream_t stream) {
    const float* src  = (const float*)d_in[0];
    const float* ln1w = (const float*)d_in[1];
    const float* ln1b = (const float*)d_in[2];
    const float* ln2w = (const float*)d_in[3];
    const float* ln2b = (const float*)d_in[4];
    const float* ln3w = (const float*)d_in[5];
    const float* ln3b = (const float*)d_in[6];
    const float* wq   = (const float*)d_in[7];
    const float* wqb  = (const float*)d_in[8];
    const float* wk   = (const float*)d_in[9];
    const float* wkb  = (const float*)d_in[10];
    const float* wv   = (const float*)d_in[11];
    const float* wvb  = (const float*)d_in[12];
    const float* wr   = (const float*)d_in[13];
    const float* wrb  = (const float*)d_in[14];
    const float* wo   = (const float*)d_in[15];
    const float* wob  = (const float*)d_in[16];
    const float* ic   = (const float*)d_in[17];
    const float* oc   = (const float*)d_in[18];
    const int* mask   = (const int*)d_in[19];
    float* out = (float*)d_out;

    // ws: srcf 8MB | zb 4 | q 4 | k 4 | v 4 | r 4 | cw24 12  = 40MB
    float* srcf = (float*)d_ws;
    unsigned short* zb = (unsigned short*)(srcf + NT);
    unsigned short* qb = zb + NT;
    unsigned short* kb = qb + NT;
    unsigned short* vb = kb + NT;   // V transposed: vt[(b*512+h*64+d)*1024+s]
    unsigned short* rb = vb + NT;
    unsigned short* cw = rb + NT;   // 24 matrices: (l*6 + {q,k,v,r,o,oc}) * DD

    WConvArgs wc;
    wc.in[0] = wq; wc.in[1] = wk; wc.in[2] = wv;
    wc.in[3] = wr; wc.in[4] = wo; wc.in[5] = oc;
    wconv24_k<<<dim3(DD / 1024, 24), dim3(256), 0, stream>>>(wc, cw);
    lncpy_k<<<dim3(NTOK / 4), dim3(256), 0, stream>>>(src, ln1w, ln1b, srcf, zb);

    for (int l = 0; l < L_; ++l) {
        unsigned short* cwl = cw + (size_t)l * 6 * DD;

        MGemm128Args ga;
        ga.A = zb;
        ga.W[0] = cwl + 0 * DD; ga.bias[0] = wqb + l * D_; ga.C[0] = qb; ga.tflag[0] = 0;
        ga.W[1] = cwl + 1 * DD; ga.bias[1] = wkb + l * D_; ga.C[1] = kb; ga.tflag[1] = 0;
        ga.W[2] = cwl + 2 * DD; ga.bias[2] = wvb + l * D_; ga.C[2] = vb; ga.tflag[2] = 1;
        ga.W[3] = cwl + 3 * DD; ga.bias[3] = wrb + l * D_; ga.C[3] = rb; ga.tflag[3] = 0;
        mgemm128_k<<<dim3(4, 32, 4), dim3(256), 0, stream>>>(ga);

        attn_k<<<dim3(32, 16), dim3(256), 0, stream>>>(qb, kb, vb, rb, mask, zb);

        MGemm64Args go;
        go.A = zb; go.W = cwl + 4 * DD; go.bias = wob + l * D_; go.res = srcf; go.C = srcf;
        mgemm64_k<<<dim3(8, 64), dim3(256), 0, stream>>>(go);

        kan_k<<<dim3(NTOK / 4), dim3(256), 0, stream>>>(
            srcf, ln2w + l * D_, ln2b + l * D_, ic + (size_t)l * D_ * 5, zb);

        MGemm64Args gk;
        gk.A = zb; gk.W = cwl + 5 * DD; gk.bias = nullptr; gk.res = srcf; gk.C = srcf;
        mgemm64_k<<<dim3(8, 64), dim3(256), 0, stream>>>(gk);

        if (l < L_ - 1)
            ln31_k<<<dim3(NTOK / 4), dim3(256), 0, stream>>>(
                srcf, ln3w + l * D_, ln3b + l * D_,
                ln1w + (l + 1) * D_, ln1b + (l + 1) * D_, srcf, zb);
        else
            ln_k<float><<<dim3(NTOK / 4), dim3(256), 0, stream>>>(
                srcf, ln3w + l * D_, ln3b + l * D_, out);
    }
}

// Round 15
// 492.987 us; speedup vs baseline: 1.0691x; 1.0691x over previous
//
#include <hip/hip_runtime.h>

// Established: all float inputs fp32, output fp32, mask int32. ws >= 256MB.
#define B_   4
#define S_   1024
#define D_   512
#define H_   8
#define DH_  64
#define L_   4
#define NTOK (B_ * S_)            // 4096 tokens
#define NT   (NTOK * D_)          // 2097152 elems per activation
#define DD   (D_ * D_)            // 262144 elems per weight matrix

typedef __attribute__((ext_vector_type(8))) short bf16x8;
typedef __attribute__((ext_vector_type(4))) float f32x4;

// async global->LDS, 16B per lane; LDS dest = wave-uniform base + lane*16
#define GLL(gp, lp)                                                            \
    __builtin_amdgcn_global_load_lds(                                          \
        (const __attribute__((address_space(1))) unsigned int*)(gp),           \
        (__attribute__((address_space(3))) unsigned int*)(lp), 16, 0, 0)

// ---------- bf16 helpers ----------
__device__ __forceinline__ float us2f(unsigned short u) {
    unsigned int v = ((unsigned int)u) << 16;
    return __uint_as_float(v);
}
__device__ __forceinline__ unsigned short f2us(float f) {
    unsigned int u = __float_as_uint(f);
    unsigned int r = (u + 0x7fffu + ((u >> 16) & 1u)) >> 16;
    return (unsigned short)r;
}
__device__ __forceinline__ unsigned short f2us_trunc(float f) {
    return (unsigned short)(__float_as_uint(f) >> 16);   // ok for f >= 0
}
__device__ __forceinline__ void stv(float* p, float v) { *p = v; }
__device__ __forceinline__ void stv(unsigned short* p, float v) { *p = f2us(v); }

// ---------- merged upfront kernel: weight conversion + src copy + first LN1 ----------
// grid.x in [0, 6144): wconv24 (y = bx>>8 selects matrix, x = bx&255 chunk)
// grid.x in [6144, 7168): lncpy for token block (bx - 6144)
struct PreArgs {
    const float* w[6];            // layer-0 base ptrs of the 6 weight tensors
    unsigned short* cw;           // 24*DD bf16 out
    const float* src;
    const float* ln1w;
    const float* ln1b;
    float* srcf;
    unsigned short* z;
};
__global__ __launch_bounds__(256) void pre_k(PreArgs a) {
    int bx = blockIdx.x;
    if (bx < 6144) {
        int y = bx >> 8;                     // matrix index 0..23 (= l*6 + t)
        int l = y / 6, tp = y - l * 6;
        int i = ((bx & 255) * 256 + threadIdx.x) * 4;
        float4 v = *(const float4*)(a.w[tp] + (size_t)l * DD + i);
        ushort4 o;
        o.x = f2us(v.x); o.y = f2us(v.y); o.z = f2us(v.z); o.w = f2us(v.w);
        *(ushort4*)(a.cw + (size_t)y * DD + i) = o;
    } else {
        int wv = threadIdx.x >> 6, lane = threadIdx.x & 63;
        int tok = (bx - 6144) * 4 + wv;
        const float* xr = a.src + (size_t)tok * D_;
        float v[8];
        float s = 0.f, s2 = 0.f;
#pragma unroll
        for (int i = 0; i < 8; ++i) {
            float t = xr[lane + 64 * i];
            v[i] = t; s += t; s2 += t * t;
        }
#pragma unroll
        for (int o = 1; o < 64; o <<= 1) { s += __shfl_xor(s, o); s2 += __shfl_xor(s2, o); }
        float mu = s * (1.f / D_);
        float var = s2 * (1.f / D_) - mu * mu;
        float rs = rsqrtf(var + 1e-5f);
#pragma unroll
        for (int i = 0; i < 8; ++i) {
            int d = lane + 64 * i;
            a.srcf[(size_t)tok * D_ + d] = v[i];
            a.z[(size_t)tok * D_ + d] = f2us((v[i] - mu) * rs * a.ln1w[d] + a.ln1b[d]);
        }
    }
}

// ---------- LayerNorm: one wave per token ----------
template <typename OutT>
__global__ __launch_bounds__(256) void ln_k(const float* __restrict__ x,
                                            const float* __restrict__ w,
                                            const float* __restrict__ b,
                                            OutT* __restrict__ y) {
    int wv = threadIdx.x >> 6, lane = threadIdx.x & 63;
    int tok = blockIdx.x * 4 + wv;
    const float* xr = x + (size_t)tok * D_;
    float v[8];
    float s = 0.f, s2 = 0.f;
#pragma unroll
    for (int i = 0; i < 8; ++i) {
        float t = xr[lane + 64 * i];
        v[i] = t; s += t; s2 += t * t;
    }
#pragma unroll
    for (int o = 1; o < 64; o <<= 1) { s += __shfl_xor(s, o); s2 += __shfl_xor(s2, o); }
    float mu = s * (1.f / D_);
    float var = s2 * (1.f / D_) - mu * mu;
    float rs = rsqrtf(var + 1e-5f);
#pragma unroll
    for (int i = 0; i < 8; ++i) {
        int d = lane + 64 * i;
        stv(y + (size_t)tok * D_ + d, (v[i] - mu) * rs * w[d] + b[d]);
    }
}

// ---------- fused LN3 (layer l) + LN1 (layer l+1): srcf -> srcf & zb ----------
__global__ __launch_bounds__(256) void ln31_k(const float* __restrict__ x,
                                              const float* __restrict__ w3,
                                              const float* __restrict__ b3,
                                              const float* __restrict__ w1,
                                              const float* __restrict__ b1,
                                              float* __restrict__ y,
                                              unsigned short* __restrict__ z) {
    int wv = threadIdx.x >> 6, lane = threadIdx.x & 63;
    int tok = blockIdx.x * 4 + wv;
    const float* xr = x + (size_t)tok * D_;
    float v[8];
    float s = 0.f, s2 = 0.f;
#pragma unroll
    for (int i = 0; i < 8; ++i) {
        float t = xr[lane + 64 * i];
        v[i] = t; s += t; s2 += t * t;
    }
#pragma unroll
    for (int o = 1; o < 64; o <<= 1) { s += __shfl_xor(s, o); s2 += __shfl_xor(s2, o); }
    float mu = s * (1.f / D_);
    float var = s2 * (1.f / D_) - mu * mu;
    float rs = rsqrtf(var + 1e-5f);
    float yv[8];
    s = 0.f; s2 = 0.f;
#pragma unroll
    for (int i = 0; i < 8; ++i) {
        int d = lane + 64 * i;
        float t = (v[i] - mu) * rs * w3[d] + b3[d];
        yv[i] = t; s += t; s2 += t * t;
    }
#pragma unroll
    for (int o = 1; o < 64; o <<= 1) { s += __shfl_xor(s, o); s2 += __shfl_xor(s2, o); }
    float mu1 = s * (1.f / D_);
    float var1 = s2 * (1.f / D_) - mu1 * mu1;
    float rs1 = rsqrtf(var1 + 1e-5f);
#pragma unroll
    for (int i = 0; i < 8; ++i) {
        int d = lane + 64 * i;
        y[(size_t)tok * D_ + d] = yv[i];
        z[(size_t)tok * D_ + d] = f2us((yv[i] - mu1) * rs1 * w1[d] + b1[d]);
    }
}

// ---------- fused LN2 + tanh + cubic B-spline -> bf16 inner ----------
__global__ __launch_bounds__(256) void kan_k(const float* __restrict__ x,
                                             const float* __restrict__ w,
                                             const float* __restrict__ b,
                                             const float* __restrict__ ic,
                                             unsigned short* __restrict__ inner) {
    int wv = threadIdx.x >> 6, lane = threadIdx.x & 63;
    int tok = blockIdx.x * 4 + wv;
    const float* xr = x + (size_t)tok * D_;
    float v[8];
    float s = 0.f, s2 = 0.f;
#pragma unroll
    for (int i = 0; i < 8; ++i) {
        float t = xr[lane + 64 * i];
        v[i] = t; s += t; s2 += t * t;
    }
#pragma unroll
    for (int o = 1; o < 64; o <<= 1) { s += __shfl_xor(s, o); s2 += __shfl_xor(s2, o); }
    float mu = s * (1.f / D_);
    float var = s2 * (1.f / D_) - mu * mu;
    float rs = rsqrtf(var + 1e-5f);

    const float kn[8] = {-1.f,
                         -0.71428571428571430f, -0.42857142857142855f, -0.14285714285714285f,
                          0.14285714285714285f,  0.42857142857142855f,  0.71428571428571430f,
                          1.f};
#pragma unroll
    for (int i = 0; i < 8; ++i) {
        int d = lane + 64 * i;
        float zv = (v[i] - mu) * rs * w[d] + b[d];
        float xt = tanhf(zv);
        float B0[5];
#pragma unroll
        for (int k = 0; k < 5; ++k) B0[k] = (kn[k] <= xt && xt < kn[k + 1]) ? 1.f : 0.f;
        float B1[4];
#pragma unroll
        for (int k = 0; k < 4; ++k)
            B1[k] = (xt - kn[k]) / (kn[k + 1] - kn[k]) * B0[k] +
                    (kn[k + 2] - xt) / (kn[k + 2] - kn[k + 1]) * B0[k + 1];
        float B2[3];
#pragma unroll
        for (int k = 0; k < 3; ++k)
            B2[k] = (xt - kn[k]) / (kn[k + 2] - kn[k]) * B1[k] +
                    (kn[k + 3] - xt) / (kn[k + 3] - kn[k + 1]) * B1[k + 1];
        float B3[2];
#pragma unroll
        for (int k = 0; k < 2; ++k)
            B3[k] = (xt - kn[k]) / (kn[k + 3] - kn[k]) * B2[k] +
                    (kn[k + 4] - xt) / (kn[k + 4] - kn[k + 1]) * B2[k + 1];
        inner[(size_t)tok * D_ + d] = f2us(B3[0] * ic[d * 5 + 0] + B3[1] * ic[d * 5 + 1]);
    }
}

// ---------- MFMA GEMM A: 128x128 tile, BK=32, single-buffered GLL (QKVR) ----------
struct MGemm128Args {
    const unsigned short* A;
    const unsigned short* W[4];
    const float* bias[4];
    unsigned short* C[4];
    int tflag[4];
};

__global__ __launch_bounds__(256) void mgemm128_k(MGemm128Args g) {
    __shared__ unsigned short As[128 * 32];
    __shared__ unsigned short Bs[128 * 32];
    int z = blockIdx.z;
    const unsigned short* W = g.W[z];
    const float* bias = g.bias[z];
    unsigned short* C = g.C[z];
    int m0 = blockIdx.y * 128, n0 = blockIdx.x * 128;
    int t = threadIdx.x;
    int wave = t >> 6, lane = t & 63;
    int wm = (wave >> 1) * 64, wn = (wave & 1) * 64;
    int l15 = lane & 15, quad = lane >> 4;
    int lrow = lane >> 2, lk = (lane & 3) * 8;

    f32x4 acc[4][4];
#pragma unroll
    for (int i = 0; i < 4; ++i)
#pragma unroll
        for (int j = 0; j < 4; ++j)
#pragma unroll
            for (int r = 0; r < 4; ++r) acc[i][j][r] = 0.f;

    int rb = wave * 32;

    for (int k0 = 0; k0 < D_; k0 += 32) {
        __syncthreads();
        GLL(g.A + (size_t)(m0 + rb + lrow) * D_ + k0 + lk,      &As[rb * 32]);
        GLL(g.A + (size_t)(m0 + rb + 16 + lrow) * D_ + k0 + lk, &As[(rb + 16) * 32]);
        GLL(W   + (size_t)(n0 + rb + lrow) * D_ + k0 + lk,      &Bs[rb * 32]);
        GLL(W   + (size_t)(n0 + rb + 16 + lrow) * D_ + k0 + lk, &Bs[(rb + 16) * 32]);
        __syncthreads();

        bf16x8 af[4], bfr[4];
#pragma unroll
        for (int mt = 0; mt < 4; ++mt)
            af[mt] = *(const bf16x8*)&As[(wm + mt * 16 + l15) * 32 + quad * 8];
#pragma unroll
        for (int nt = 0; nt < 4; ++nt)
            bfr[nt] = *(const bf16x8*)&Bs[(wn + nt * 16 + l15) * 32 + quad * 8];
#pragma unroll
        for (int mt = 0; mt < 4; ++mt)
#pragma unroll
            for (int nt = 0; nt < 4; ++nt)
                acc[mt][nt] = __builtin_amdgcn_mfma_f32_16x16x32_bf16(
                    af[mt], bfr[nt], acc[mt][nt], 0, 0, 0);
    }

    if (g.tflag[z]) {
#pragma unroll
        for (int mt = 0; mt < 4; ++mt)
#pragma unroll
            for (int nt = 0; nt < 4; ++nt) {
                int n = n0 + wn + nt * 16 + l15;
                float bv = bias[n];
                int m = m0 + wm + mt * 16 + quad * 4;
                ushort4 pk;
                pk.x = f2us(acc[mt][nt][0] + bv);
                pk.y = f2us(acc[mt][nt][1] + bv);
                pk.z = f2us(acc[mt][nt][2] + bv);
                pk.w = f2us(acc[mt][nt][3] + bv);
                *(ushort4*)(C + ((size_t)(m >> 10) * 512 + n) * 1024 + (m & 1023)) = pk;
            }
    } else {
#pragma unroll
        for (int mt = 0; mt < 4; ++mt)
#pragma unroll
            for (int nt = 0; nt < 4; ++nt) {
                int n = n0 + wn + nt * 16 + l15;
                float bv = bias[n];
#pragma unroll
                for (int r = 0; r < 4; ++r) {
                    int m = m0 + wm + mt * 16 + quad * 4 + r;
                    C[(size_t)m * D_ + n] = f2us(acc[mt][nt][r] + bv);
                }
            }
    }
}

// ---------- MFMA GEMM B: 64x64 tile, VGPR-staged (wo/oc; 512 blocks) ----------
struct MGemm64Args {
    const unsigned short* A;
    const unsigned short* W;
    const float* bias;
    const float* res;
    float* C;
};

__global__ __launch_bounds__(256) void mgemm64_k(MGemm64Args g) {
    __shared__ unsigned short As[64][40];
    __shared__ unsigned short Bs[64][40];
    int m0 = blockIdx.y * 64, n0 = blockIdx.x * 64;
    int t = threadIdx.x;
    int wave = t >> 6, lane = t & 63;
    int wm = (wave >> 1) * 32, wn = (wave & 1) * 32;
    int lrow = t >> 2, lk = (t & 3) * 8;
    const unsigned short* Ag = g.A + (size_t)(m0 + lrow) * D_ + lk;
    const unsigned short* Wg = g.W + (size_t)(n0 + lrow) * D_ + lk;

    f32x4 acc[2][2];
#pragma unroll
    for (int i = 0; i < 2; ++i)
#pragma unroll
        for (int j = 0; j < 2; ++j)
#pragma unroll
            for (int r = 0; r < 4; ++r) acc[i][j][r] = 0.f;

    int fm = lane & 15, fq = (lane >> 4) * 8;

    for (int k0 = 0; k0 < D_; k0 += 32) {
        uint4 a = *(const uint4*)(Ag + k0);
        uint4 b = *(const uint4*)(Wg + k0);
        __syncthreads();
        *(uint4*)&As[lrow][lk] = a;
        *(uint4*)&Bs[lrow][lk] = b;
        __syncthreads();
        bf16x8 a0 = *(const bf16x8*)&As[wm + fm][fq];
        bf16x8 a1 = *(const bf16x8*)&As[wm + 16 + fm][fq];
        bf16x8 b0 = *(const bf16x8*)&Bs[wn + fm][fq];
        bf16x8 b1 = *(const bf16x8*)&Bs[wn + 16 + fm][fq];
        acc[0][0] = __builtin_amdgcn_mfma_f32_16x16x32_bf16(a0, b0, acc[0][0], 0, 0, 0);
        acc[0][1] = __builtin_amdgcn_mfma_f32_16x16x32_bf16(a0, b1, acc[0][1], 0, 0, 0);
        acc[1][0] = __builtin_amdgcn_mfma_f32_16x16x32_bf16(a1, b0, acc[1][0], 0, 0, 0);
        acc[1][1] = __builtin_amdgcn_mfma_f32_16x16x32_bf16(a1, b1, acc[1][1], 0, 0, 0);
    }

    int col = lane & 15, rbase = (lane >> 4) * 4;
#pragma unroll
    for (int i = 0; i < 2; ++i)
#pragma unroll
        for (int j = 0; j < 2; ++j) {
            int n = n0 + wn + j * 16 + col;
            float bv = g.bias ? g.bias[n] : 0.f;
#pragma unroll
            for (int r = 0; r < 4; ++r) {
                int m = m0 + wm + i * 16 + rbase + r;
                g.C[(size_t)m * D_ + n] = acc[i][j][r] + bv + g.res[(size_t)m * D_ + n];
            }
        }
}

// ---------- MFMA flash attention, softmax-lite, single-buffer GLL K/V ----------
// XOR swizzle on GLOBAL source chunk (LDS chunk j of row r holds global chunk
// j ^ (r&7)); frag reads use chunk ((kc*4+quad) ^ (l15&7)). Mask staged once.
// p computed as exp2(s*0.125*log2e + M) via v_exp_f32; P packed by truncation.
// vt layout: vt[(b*512 + h*64 + d)*1024 + s]
__global__ __launch_bounds__(256) void attn_k(const unsigned short* __restrict__ Q,
                                              const unsigned short* __restrict__ K,
                                              const unsigned short* __restrict__ vt,
                                              const unsigned short* __restrict__ R,
                                              const int* __restrict__ mask,
                                              unsigned short* __restrict__ O) {
    __shared__ unsigned short Ks[64 * 64];
    __shared__ unsigned short Vts[64 * 64];
    __shared__ unsigned short Ps[4][16][72];
    __shared__ float Ms[1024];

    int bh = blockIdx.x;
    int b = bh >> 3, h = bh & 7;
    int qt0 = blockIdx.y * 64;
    int t = threadIdx.x, wave = t >> 6, lane = t & 63;
    int l15 = lane & 15, quad = lane >> 4;
    int qw0 = qt0 + wave * 16;

    const unsigned short* Qrow = Q + ((size_t)(b * S_ + qw0 + l15) * H_ + h) * DH_;
    bf16x8 qf[2];
    qf[0] = *(const bf16x8*)(Qrow + quad * 8);
    qf[1] = *(const bf16x8*)(Qrow + 32 + quad * 8);

    // stage whole mask row once
#pragma unroll
    for (int u = 0; u < 4; ++u)
        Ms[u * 256 + t] = mask[b * S_ + u * 256 + t] ? 0.f : -1e10f;

    float lsum[4] = {0.f, 0.f, 0.f, 0.f};
    f32x4 acc_o[4];
#pragma unroll
    for (int dt = 0; dt < 4; ++dt)
#pragma unroll
        for (int r = 0; r < 4; ++r) acc_o[dt][r] = 0.f;

    int lro = lane >> 3;
    int cglob = (lane & 7) ^ lro;
    const unsigned short* kgp0 =
        K + ((size_t)(b * S_ + wave * 16 + lro) * H_ + h) * DH_ + cglob * 8;
    const unsigned short* vgp0 =
        vt + (size_t)(b * 512 + h * 64 + wave * 16 + lro) * 1024 + cglob * 8;
    int swz = l15 & 7;
    const float SC = 0.125f * 1.44269504089f;   // fold softmax scale into exp2

    for (int kt = 0; kt < 16; ++kt) {
        __syncthreads();
        GLL(kgp0 + (size_t)kt * 64 * 512,             &Ks[(wave * 16) * 64]);
        GLL(kgp0 + (size_t)kt * 64 * 512 + 8 * 512,   &Ks[(wave * 16 + 8) * 64]);
        GLL(vgp0 + kt * 64,                           &Vts[(wave * 16) * 64]);
        GLL(vgp0 + kt * 64 + 8 * 1024,                &Vts[(wave * 16 + 8) * 64]);
        __syncthreads();

        // S = Q @ K^T
        f32x4 accs[4];
#pragma unroll
        for (int jt = 0; jt < 4; ++jt)
#pragma unroll
            for (int r = 0; r < 4; ++r) accs[jt][r] = 0.f;
#pragma unroll
        for (int kc = 0; kc < 2; ++kc) {
            int ch = ((kc * 4 + quad) ^ swz) * 8;
#pragma unroll
            for (int jt = 0; jt < 4; ++jt) {
                bf16x8 kf = *(const bf16x8*)&Ks[(jt * 16 + l15) * 64 + ch];
                accs[jt] = __builtin_amdgcn_mfma_f32_16x16x32_bf16(qf[kc], kf, accs[jt], 0, 0, 0);
            }
        }

        // softmax-lite (v_exp_f32 computes 2^x)
#pragma unroll
        for (int jt = 0; jt < 4; ++jt) {
            float madd = Ms[kt * 64 + jt * 16 + l15];
#pragma unroll
            for (int r = 0; r < 4; ++r) {
                float p = __builtin_amdgcn_exp2f(accs[jt][r] * SC + madd);
                lsum[r] += p;
                Ps[wave][quad * 4 + r][jt * 16 + l15] = f2us_trunc(p);
            }
        }

        // O += P @ V
#pragma unroll
        for (int kc = 0; kc < 2; ++kc) {
            bf16x8 pf = *(const bf16x8*)&Ps[wave][l15][kc * 32 + quad * 8];
            int ch = ((kc * 4 + quad) ^ swz) * 8;
#pragma unroll
            for (int dt = 0; dt < 4; ++dt) {
                bf16x8 vf = *(const bf16x8*)&Vts[(dt * 16 + l15) * 64 + ch];
                acc_o[dt] = __builtin_amdgcn_mfma_f32_16x16x32_bf16(pf, vf, acc_o[dt], 0, 0, 0);
            }
        }
    }

#pragma unroll
    for (int off = 1; off < 16; off <<= 1)
#pragma unroll
        for (int r = 0; r < 4; ++r) lsum[r] += __shfl_xor(lsum[r], off);

#pragma unroll
    for (int r = 0; r < 4; ++r) {
        int q = qw0 + quad * 4 + r;
        float inv = 1.f / lsum[r];
        const unsigned short* Rr = R + ((size_t)(b * S_ + q) * H_ + h) * DH_;
        unsigned short* Or = O + ((size_t)(b * S_ + q) * H_ + h) * DH_;
#pragma unroll
        for (int dt = 0; dt < 4; ++dt) {
            int d = dt * 16 + l15;
            Or[d] = f2us(acc_o[dt][r] * inv * us2f(Rr[d]));
        }
    }
}

extern "C" void kernel_launch(void* const* d_in, const int* in_sizes, int n_in,
                              void* d_out, int out_size, void* d_ws, size_t ws_size,
                              hipStream_t stream) {
    const float* src  = (const float*)d_in[0];
    const float* ln1w = (const float*)d_in[1];
    const float* ln1b = (const float*)d_in[2];
    const float* ln2w = (const float*)d_in[3];
    const float* ln2b = (const float*)d_in[4];
    const float* ln3w = (const float*)d_in[5];
    const float* ln3b = (const float*)d_in[6];
    const float* wq   = (const float*)d_in[7];
    const float* wqb  = (const float*)d_in[8];
    const float* wk   = (const float*)d_in[9];
    const float* wkb  = (const float*)d_in[10];
    const float* wv   = (const float*)d_in[11];
    const float* wvb  = (const float*)d_in[12];
    const float* wr   = (const float*)d_in[13];
    const float* wrb  = (const float*)d_in[14];
    const float* wo   = (const float*)d_in[15];
    const float* wob  = (const float*)d_in[16];
    const float* ic   = (const float*)d_in[17];
    const float* oc   = (const float*)d_in[18];
    const int* mask   = (const int*)d_in[19];
    float* out = (float*)d_out;

    // ws: srcf 8MB | zb 4 | q 4 | k 4 | v 4 | r 4 | cw24 12  = 40MB
    float* srcf = (float*)d_ws;
    unsigned short* zb = (unsigned short*)(srcf + NT);
    unsigned short* qb = zb + NT;
    unsigned short* kb = qb + NT;
    unsigned short* vb = kb + NT;   // V transposed: vt[(b*512+h*64+d)*1024+s]
    unsigned short* rb = vb + NT;
    unsigned short* cw = rb + NT;   // 24 matrices: (l*6 + {q,k,v,r,o,oc}) * DD

    PreArgs pa;
    pa.w[0] = wq; pa.w[1] = wk; pa.w[2] = wv;
    pa.w[3] = wr; pa.w[4] = wo; pa.w[5] = oc;
    pa.cw = cw; pa.src = src; pa.ln1w = ln1w; pa.ln1b = ln1b;
    pa.srcf = srcf; pa.z = zb;
    pre_k<<<dim3(6144 + NTOK / 4), dim3(256), 0, stream>>>(pa);

    for (int l = 0; l < L_; ++l) {
        unsigned short* cwl = cw + (size_t)l * 6 * DD;

        MGemm128Args ga;
        ga.A = zb;
        ga.W[0] = cwl + 0 * DD; ga.bias[0] = wqb + l * D_; ga.C[0] = qb; ga.tflag[0] = 0;
        ga.W[1] = cwl + 1 * DD; ga.bias[1] = wkb + l * D_; ga.C[1] = kb; ga.tflag[1] = 0;
        ga.W[2] = cwl + 2 * DD; ga.bias[2] = wvb + l * D_; ga.C[2] = vb; ga.tflag[2] = 1;
        ga.W[3] = cwl + 3 * DD; ga.bias[3] = wrb + l * D_; ga.C[3] = rb; ga.tflag[3] = 0;
        mgemm128_k<<<dim3(4, 32, 4), dim3(256), 0, stream>>>(ga);

        attn_k<<<dim3(32, 16), dim3(256), 0, stream>>>(qb, kb, vb, rb, mask, zb);

        MGemm64Args go;
        go.A = zb; go.W = cwl + 4 * DD; go.bias = wob + l * D_; go.res = srcf; go.C = srcf;
        mgemm64_k<<<dim3(8, 64), dim3(256), 0, stream>>>(go);

        kan_k<<<dim3(NTOK / 4), dim3(256), 0, stream>>>(
            srcf, ln2w + l * D_, ln2b + l * D_, ic + (size_t)l * D_ * 5, zb);

        MGemm64Args gk;
        gk.A = zb; gk.W = cwl + 5 * DD; gk.bias = nullptr; gk.res = srcf; gk.C = srcf;
        mgemm64_k<<<dim3(8, 64), dim3(256), 0, stream>>>(gk);

        if (l < L_ - 1)
            ln31_k<<<dim3(NTOK / 4), dim3(256), 0, stream>>>(
                srcf, ln3w + l * D_, ln3b + l * D_,
                ln1w + (l + 1) * D_, ln1b + (l + 1) * D_, srcf, zb);
        else
            ln_k<float><<<dim3(NTOK / 4), dim3(256), 0, stream>>>(
                srcf, ln3w + l * D_, ln3b + l * D_, out);
    }
}